// Round 1
// baseline (6439.587 us; speedup 1.0000x reference)
//
#include <hip/hip_runtime.h>
#include <math.h>

#define N_NODES 20000
#define T_TYPES 4
#define H_DIM   256
#define E_EDGES 160000
#define EK_EDGES 40000

__device__ __forceinline__ float silu_f(float x) {
    return x / (1.0f + __expf(-x));
}

// ---------------- node_emb: ne[n,f] = sum_t h[n,t,f]*nc_w[t] + nc_b ----------
__global__ __launch_bounds__(256) void ne_kernel(const float* __restrict__ h,
    const float* __restrict__ nc_w, const float* __restrict__ nc_b,
    float* __restrict__ ne)
{
    int idx = blockIdx.x * 256 + threadIdx.x;
    if (idx >= N_NODES * H_DIM) return;
    int n = idx >> 8, f = idx & 255;
    const float* hp = h + (size_t)n * 1024 + f;
    float v = hp[0] * nc_w[0] + hp[256] * nc_w[1] + hp[512] * nc_w[2]
            + hp[768] * nc_w[3] + nc_b[0];
    ne[idx] = v;
}

// ---------------- gather x = [ne[src] || ne[tgt]] for an edge chunk ----------
__global__ __launch_bounds__(256) void gather_kernel(const float* __restrict__ ne,
    const int* __restrict__ eidx, int base, int ch, float* __restrict__ x)
{
    int idx = blockIdx.x * 256 + threadIdx.x;
    if (idx >= ch * 512) return;
    int i = idx >> 9, f = idx & 511;
    int eg = base + i;
    int node = (f < 256) ? eidx[eg] : eidx[E_EDGES + eg];
    x[idx] = ne[(size_t)node * 256 + (f & 255)];
}

// ---------------- generic fp32 tiled GEMM: C = act(A@W + b) (+R) -------------
// A [M,K] rowmajor, W [K,Nc] rowmajor, bias [Nc], R optional residual [M,Nc]
// BM=BN=64, BK=32, 256 threads, 4x4 acc per thread.
#define GBK 32
#define SPITCH 68   // float4-aligned, 2-way-max bank aliasing

__global__ __launch_bounds__(256) void gemm_kernel(
    const float* __restrict__ A, const float* __restrict__ W,
    const float* __restrict__ bias, const float* __restrict__ R,
    float* __restrict__ C, int M, int K, int Nc, int act)
{
    __shared__ float As[GBK][SPITCH];  // [kk][row]  (A transposed tile)
    __shared__ float Ws[GBK][SPITCH];  // [kk][col]
    int tid = threadIdx.x;
    int row0 = blockIdx.y * 64;
    int col0 = blockIdx.x * 64;
    int tx = tid & 15, ty = tid >> 4;
    float acc[4][4] = {};

    for (int k0 = 0; k0 < K; k0 += GBK) {
        // stage A-tile: 64 rows x 32 k = 512 float4, 2 per thread
        #pragma unroll
        for (int i = 0; i < 2; i++) {
            int q = tid + i * 256;
            int row = q >> 3;       // 8 float4 per row
            int kc = q & 7;
            int grow = row0 + row;
            float4 v = make_float4(0.f, 0.f, 0.f, 0.f);
            if (grow < M) v = *(const float4*)(A + (size_t)grow * K + k0 + kc * 4);
            As[kc * 4 + 0][row] = v.x;
            As[kc * 4 + 1][row] = v.y;
            As[kc * 4 + 2][row] = v.z;
            As[kc * 4 + 3][row] = v.w;
        }
        // stage W-tile: 32 k x 64 cols = 512 float4, 2 per thread
        #pragma unroll
        for (int i = 0; i < 2; i++) {
            int q = tid + i * 256;
            int kk = q >> 4;        // 16 float4 per k-row
            int jc = q & 15;
            float4 v = *(const float4*)(W + (size_t)(k0 + kk) * Nc + col0 + jc * 4);
            *(float4*)&Ws[kk][jc * 4] = v;
        }
        __syncthreads();
        #pragma unroll
        for (int kk = 0; kk < GBK; kk++) {
            float4 av = *(const float4*)&As[kk][ty * 4];
            float4 wv = *(const float4*)&Ws[kk][tx * 4];
            const float* ap = &av.x;
            const float* wp = &wv.x;
            #pragma unroll
            for (int a = 0; a < 4; a++)
                #pragma unroll
                for (int b = 0; b < 4; b++)
                    acc[a][b] += ap[a] * wp[b];
        }
        __syncthreads();
    }

    float4 bv = *(const float4*)(bias + col0 + tx * 4);
    const float* bp = &bv.x;
    #pragma unroll
    for (int a = 0; a < 4; a++) {
        int grow = row0 + ty * 4 + a;
        if (grow >= M) continue;
        size_t coff = (size_t)grow * Nc + col0 + tx * 4;
        float4 rv = make_float4(0.f, 0.f, 0.f, 0.f);
        if (R) rv = *(const float4*)(R + coff);
        float4 o;
        float* op = &o.x;
        const float* rp = &rv.x;
        #pragma unroll
        for (int b = 0; b < 4; b++) {
            float v = acc[a][b] + bp[b];
            if (act) v = silu_f(v);
            if (R) v += rp[b];
            op[b] = v;
        }
        *(float4*)(C + coff) = o;
    }
}

// ---------------- GINE message + atomic segment-sum --------------------------
// grid = T*EK/4 blocks, 256 threads; wave (64 lanes) per edge, float4 per lane
__global__ __launch_bounds__(256) void msg_kernel(
    const float* __restrict__ h, const float* __restrict__ mij,
    const int* __restrict__ eidx, const int* __restrict__ emask,
    float* __restrict__ agg)
{
    int e4 = blockIdx.x * 4 + (threadIdx.x >> 6);   // index into [T*EK]
    int t = e4 / EK_EDGES;
    int em = emask[e4];
    int src = eidx[em];
    int dst = eidx[E_EDGES + em];
    int f = (threadIdx.x & 63) * 4;
    float4 hv = *(const float4*)(h + (size_t)src * 1024 + t * 256 + f);
    float4 mv = *(const float4*)(mij + (size_t)em * 256 + f);
    float4 s;
    s.x = silu_f(hv.x + mv.x);
    s.y = silu_f(hv.y + mv.y);
    s.z = silu_f(hv.z + mv.z);
    s.w = silu_f(hv.w + mv.w);
    float* ap = agg + ((size_t)t * N_NODES + dst) * 256 + f;
    atomicAdd(ap + 0, s.x);
    atomicAdd(ap + 1, s.y);
    atomicAdd(ap + 2, s.z);
    atomicAdd(ap + 3, s.w);
}

// ---------------- z = agg + xb (in place into agg) ---------------------------
__global__ __launch_bounds__(256) void addxb_kernel(const float* __restrict__ h,
                                                    float* __restrict__ agg)
{
    int idx = blockIdx.x * 256 + threadIdx.x;       // float4 index
    if (idx >= T_TYPES * N_NODES * H_DIM / 4) return;
    int fidx = idx * 4;
    int t = fidx / (N_NODES * H_DIM);
    int r = fidx - t * (N_NODES * H_DIM);
    int n = r >> 8, f = r & 255;
    float4 a = *(float4*)(agg + fidx);
    float4 hv = *(const float4*)(h + (size_t)n * 1024 + t * 256 + f);
    a.x += hv.x; a.y += hv.y; a.z += hv.z; a.w += hv.w;
    *(float4*)(agg + fidx) = a;
}

// ---------------- hid (xa layout [N,T,H]): silu(z[t,n,f]) + h[n,t,f] ---------
__global__ __launch_bounds__(256) void hid_kernel(const float* __restrict__ h,
    const float* __restrict__ z, float* __restrict__ hid)
{
    int idx = blockIdx.x * 256 + threadIdx.x;       // float4 index
    if (idx >= N_NODES * T_TYPES * H_DIM / 4) return;
    int fidx = idx * 4;
    int n = fidx >> 10;
    int t = (fidx >> 8) & 3;
    int f = fidx & 255;
    float4 zv = *(const float4*)(z + ((size_t)t * N_NODES + n) * 256 + f);
    float4 hv = *(const float4*)(h + fidx);
    float4 o;
    o.x = silu_f(zv.x) + hv.x;
    o.y = silu_f(zv.y) + hv.y;
    o.z = silu_f(zv.z) + hv.z;
    o.w = silu_f(zv.w) + hv.w;
    *(float4*)(hid + fidx) = o;
}

// ---------------- fused per-node attention (T=4 tokens, 32 heads x 8 dim) ----
__global__ __launch_bounds__(256) void attn_kernel(const float* __restrict__ hid,
    const float* __restrict__ wq, const float* __restrict__ bq,
    const float* __restrict__ wk, const float* __restrict__ bk,
    const float* __restrict__ wv, const float* __restrict__ bv,
    const float* __restrict__ wo, const float* __restrict__ bo,
    float* __restrict__ out)
{
    __shared__ float xa[4][256], qs[4][256], ks[4][256], vs[4][256], os[4][256];
    int n = blockIdx.x;
    int tid = threadIdx.x;
    const float* base = hid + (size_t)n * 1024;
    ((float4*)&xa[0][0])[tid] = ((const float4*)base)[tid];
    __syncthreads();

    // q,k,v projections: thread = output column
    float aq[4] = {}, ak[4] = {}, av[4] = {};
    for (int k = 0; k < 256; k++) {
        float wqv = wq[k * 256 + tid];
        float wkv = wk[k * 256 + tid];
        float wvv = wv[k * 256 + tid];
        #pragma unroll
        for (int t = 0; t < 4; t++) {
            float x = xa[t][k];
            aq[t] += x * wqv; ak[t] += x * wkv; av[t] += x * wvv;
        }
    }
    #pragma unroll
    for (int t = 0; t < 4; t++) {
        qs[t][tid] = aq[t] + bq[tid];
        ks[t][tid] = ak[t] + bk[tid];
        vs[t][tid] = av[t] + bv[tid];
    }
    __syncthreads();

    if (tid < 128) {   // thread = (head, query-token)
        int hh = tid >> 2, i = tid & 3;
        int d0 = hh * 8;
        const float scale = 0.35355339059327373f;   // 1/sqrt(8)
        float s[4];
        #pragma unroll
        for (int j = 0; j < 4; j++) {
            float acc = 0.f;
            #pragma unroll
            for (int d = 0; d < 8; d++) acc += qs[i][d0 + d] * ks[j][d0 + d];
            s[j] = acc * scale;
        }
        float m = fmaxf(fmaxf(s[0], s[1]), fmaxf(s[2], s[3]));
        float e[4], sum = 0.f;
        #pragma unroll
        for (int j = 0; j < 4; j++) { e[j] = __expf(s[j] - m); sum += e[j]; }
        float inv = 1.0f / sum;
        #pragma unroll
        for (int d = 0; d < 8; d++) {
            float acc = 0.f;
            #pragma unroll
            for (int j = 0; j < 4; j++) acc += e[j] * inv * vs[j][d0 + d];
            os[i][d0 + d] = acc;
        }
    }
    __syncthreads();

    // output projection + residual
    float ao[4] = {};
    for (int k = 0; k < 256; k++) {
        float wov = wo[k * 256 + tid];
        #pragma unroll
        for (int t = 0; t < 4; t++) ao[t] += os[t][k] * wov;
    }
    #pragma unroll
    for (int t = 0; t < 4; t++)
        out[(size_t)n * 1024 + t * 256 + tid] = ao[t] + bo[tid] + xa[t][tid];
}

// =============================================================================
extern "C" void kernel_launch(void* const* d_in, const int* in_sizes, int n_in,
                              void* d_out, int out_size, void* d_ws, size_t ws_size,
                              hipStream_t stream)
{
    (void)in_sizes; (void)n_in; (void)out_size;
    const float* h     = (const float*)d_in[0];
    const int*   eidx  = (const int*)d_in[1];
    const int*   emask = (const int*)d_in[2];
    const float* nc_w  = (const float*)d_in[3];
    const float* nc_b  = (const float*)d_in[4];
    const float* em_w1 = (const float*)d_in[5];
    const float* em_b1 = (const float*)d_in[6];
    const float* em_w2 = (const float*)d_in[7];
    const float* em_b2 = (const float*)d_in[8];
    const float* em_w3 = (const float*)d_in[9];
    const float* em_b3 = (const float*)d_in[10];
    const float* conv_w = (const float*)d_in[11];
    const float* conv_b = (const float*)d_in[12];
    const float* wq = (const float*)d_in[13]; const float* bq = (const float*)d_in[14];
    const float* wk = (const float*)d_in[15]; const float* bk = (const float*)d_in[16];
    const float* wv = (const float*)d_in[17]; const float* bv = (const float*)d_in[18];
    const float* wo = (const float*)d_in[19]; const float* bo = (const float*)d_in[20];

    float* out = (float*)d_out;                                  // [N,T,H]
    float* mij = out + (size_t)N_NODES * T_TYPES * H_DIM;        // [E,H]

    // workspace layout (floats)
    float* ws = (float*)d_ws;
    size_t off = 0;
    float* ne  = ws + off; off += (size_t)N_NODES * H_DIM;            // 5.12M
    float* agg = ws + off; off += (size_t)T_TYPES * N_NODES * H_DIM;  // 20.48M (z)
    float* p1  = ws + off; off += (size_t)N_NODES * H_DIM;
    float* p2  = ws + off; off += (size_t)N_NODES * H_DIM;
    float* hid = ws + off; off += (size_t)N_NODES * T_TYPES * H_DIM;
    size_t fixed = off;
    // adaptive edge-chunk size (all divide E evenly)
    const int cands[8] = {20000, 16000, 10000, 8000, 5000, 4000, 2000, 1000};
    int CH = 1000;
    for (int i = 0; i < 8; i++) {
        if ((fixed + (size_t)cands[i] * 1792) * 4 <= ws_size) { CH = cands[i]; break; }
    }
    float* cx  = ws + off;
    float* ch1 = cx + (size_t)CH * 512;
    float* ch2 = ch1 + (size_t)CH * 768;

    hipMemsetAsync(agg, 0, (size_t)T_TYPES * N_NODES * H_DIM * 4, stream);

    ne_kernel<<<(N_NODES * H_DIM) / 256, 256, 0, stream>>>(h, nc_w, nc_b, ne);

    // edge MLP in chunks: gather -> 512->768->512->256
    int nchunks = E_EDGES / CH;
    for (int c = 0; c < nchunks; c++) {
        int base = c * CH;
        gather_kernel<<<(CH * 512) / 256, 256, 0, stream>>>(ne, eidx, base, CH, cx);
        dim3 g1(768 / 64, (CH + 63) / 64);
        gemm_kernel<<<g1, 256, 0, stream>>>(cx, em_w1, em_b1, nullptr, ch1, CH, 512, 768, 1);
        dim3 g2(512 / 64, (CH + 63) / 64);
        gemm_kernel<<<g2, 256, 0, stream>>>(ch1, em_w2, em_b2, nullptr, ch2, CH, 768, 512, 1);
        dim3 g3(256 / 64, (CH + 63) / 64);
        gemm_kernel<<<g3, 256, 0, stream>>>(ch2, em_w3, em_b3, nullptr,
                                            mij + (size_t)base * 256, CH, 512, 256, 0);
    }

    // GINE: message + scatter, then z = agg + xb
    msg_kernel<<<(T_TYPES * EK_EDGES) / 4, 256, 0, stream>>>(h, mij, eidx, emask, agg);
    addxb_kernel<<<(T_TYPES * N_NODES * H_DIM / 4) / 256, 256, 0, stream>>>(h, agg);

    // conv MLP: per type, 4 residual layers, ping-pong p1/p2, write back into agg
    for (int t = 0; t < T_TYPES; t++) {
        float* zt = agg + (size_t)t * N_NODES * H_DIM;
        const float* cw = conv_w + (size_t)t * 4 * H_DIM * H_DIM;
        const float* cb = conv_b + (size_t)t * 4 * H_DIM;
        dim3 g(256 / 64, (N_NODES + 63) / 64);
        gemm_kernel<<<g, 256, 0, stream>>>(zt, cw,              cb,       zt, p1, N_NODES, 256, 256, 1);
        gemm_kernel<<<g, 256, 0, stream>>>(p1, cw + 65536,      cb + 256, p1, p2, N_NODES, 256, 256, 1);
        gemm_kernel<<<g, 256, 0, stream>>>(p2, cw + 131072,     cb + 512, p2, p1, N_NODES, 256, 256, 1);
        gemm_kernel<<<g, 256, 0, stream>>>(p1, cw + 196608,     cb + 768, p1, zt, N_NODES, 256, 256, 0);
    }

    hid_kernel<<<(N_NODES * T_TYPES * H_DIM / 4) / 256, 256, 0, stream>>>(h, agg, hid);

    attn_kernel<<<N_NODES, 256, 0, stream>>>(hid, wq, bq, wk, bk, wv, bv, wo, bo, out);
}

// Round 3
// 3069.833 us; speedup vs baseline: 2.0977x; 2.0977x over previous
//
#include <hip/hip_runtime.h>
#include <math.h>

#define N_NODES 20000
#define T_TYPES 4
#define H_DIM   256
#define E_EDGES 160000
#define EK_EDGES 40000
#define CH_EDGE 16000

typedef __attribute__((ext_vector_type(8))) short short8v;
typedef __attribute__((ext_vector_type(8))) unsigned short ushort8v;
typedef __attribute__((ext_vector_type(4))) float f32x4;

__device__ __forceinline__ float silu_f(float x) {
    return x / (1.0f + __expf(-x));
}
__device__ __forceinline__ float b2f(unsigned short u) {
    union { unsigned int i; float f; } v; v.i = ((unsigned int)u) << 16; return v.f;
}
__device__ __forceinline__ unsigned short f2b(float f) {
    union { unsigned int i; float f; } v; v.f = f;
    unsigned int r = v.i + 0x7FFF + ((v.i >> 16) & 1);
    return (unsigned short)(r >> 16);
}

#if __has_builtin(__builtin_amdgcn_global_load_lds)
#define HAS_GLL 1
#define GLOAD16(g, l) __builtin_amdgcn_global_load_lds( \
    (const __attribute__((address_space(1))) void*)(g), \
    (__attribute__((address_space(3))) void*)(l), 16, 0, 0)
#else
#define HAS_GLL 0
#endif

// ---------------- weight transpose+convert: W [K,N] f32 -> Wt [N,K] bf16 -----
__global__ __launch_bounds__(256) void wtrans_kernel(const float* __restrict__ W,
    unsigned short* __restrict__ Wt, int K, int N, long sW, long sWt)
{
    __shared__ float tile[32][33];
    const float* Wz = W + (size_t)blockIdx.z * sW;
    unsigned short* Wtz = Wt + (size_t)blockIdx.z * sWt;
    int tx = threadIdx.x & 31, ty = threadIdx.x >> 5;
    #pragma unroll
    for (int r = ty; r < 32; r += 8) {
        int gr = blockIdx.y * 32 + r, gc = blockIdx.x * 32 + tx;
        tile[r][tx] = Wz[(size_t)gr * N + gc];
    }
    __syncthreads();
    #pragma unroll
    for (int r = ty; r < 32; r += 8) {
        int gn = blockIdx.x * 32 + r, gk = blockIdx.y * 32 + tx;
        Wtz[(size_t)gn * K + gk] = f2b(tile[tx][r]);
    }
}

// ---------------- node_emb -> bf16 ------------------------------------------
__global__ __launch_bounds__(256) void ne_kernel(const float* __restrict__ h,
    const float* __restrict__ nc_w, const float* __restrict__ nc_b,
    unsigned short* __restrict__ neb)
{
    int idx = blockIdx.x * 256 + threadIdx.x;         // per 4 features
    if (idx >= N_NODES * 64) return;
    int n = idx >> 6, f4 = (idx & 63) * 4;
    const float* hp = h + (size_t)n * 1024 + f4;
    float4 a = *(const float4*)hp;
    float4 b = *(const float4*)(hp + 256);
    float4 c = *(const float4*)(hp + 512);
    float4 d = *(const float4*)(hp + 768);
    float w0 = nc_w[0], w1 = nc_w[1], w2 = nc_w[2], w3 = nc_w[3], bb = nc_b[0];
    ushort4 o;
    o.x = f2b(a.x * w0 + b.x * w1 + c.x * w2 + d.x * w3 + bb);
    o.y = f2b(a.y * w0 + b.y * w1 + c.y * w2 + d.y * w3 + bb);
    o.z = f2b(a.z * w0 + b.z * w1 + c.z * w2 + d.z * w3 + bb);
    o.w = f2b(a.w * w0 + b.w * w1 + c.w * w2 + d.w * w3 + bb);
    *(ushort4*)(neb + (size_t)n * 256 + f4) = o;
}

// ---------------- gather [ne[src]||ne[tgt]] bf16 for an edge chunk -----------
__global__ __launch_bounds__(256) void gather_kernel(const unsigned short* __restrict__ neb,
    const int* __restrict__ eidx, int base, unsigned short* __restrict__ cx)
{
    int idx = blockIdx.x * 256 + threadIdx.x;         // per 8 bf16
    int row = idx >> 6, f8 = idx & 63;
    int e = base + row;
    int node = (f8 < 32) ? eidx[e] : eidx[E_EDGES + e];
    ushort8v v = *(const ushort8v*)(neb + (size_t)node * 256 + (f8 & 31) * 8);
    *(ushort8v*)(cx + (size_t)row * 512 + f8 * 8) = v;
}

// ---------------- bf16 MFMA GEMM: C = act(A@Bt^T + bias) (+Rf f32) -----------
// A [M,K] bf16 rowmajor (rows up to next 128-mult must be readable),
// Bt [Nc,K] bf16 rowmajor, bias f32 [Nc], Rf optional f32 residual.
// Dual store: Cf (f32) and/or Cb (bf16).
__global__ __launch_bounds__(256) void mfma_gemm(
    const unsigned short* __restrict__ A, const unsigned short* __restrict__ Bt,
    const float* __restrict__ bias, const float* __restrict__ Rf,
    float* __restrict__ Cf, unsigned short* __restrict__ Cb,
    int M, int K, int Nc, int act)
{
    __shared__ unsigned short As[4096];   // chunk c = k8*128+row, 8 elts (16B)
    __shared__ unsigned short Bs[4096];
    int tid = threadIdx.x;
    int wid = tid >> 6, lane = tid & 63;
    int row0 = blockIdx.y * 128, col0 = blockIdx.x * 128;
    int wm = (wid >> 1) * 64, wn = (wid & 1) * 64;

    f32x4 acc[4][4];
    #pragma unroll
    for (int i = 0; i < 4; i++)
        #pragma unroll
        for (int j = 0; j < 4; j++)
            acc[i][j] = (f32x4){0.f, 0.f, 0.f, 0.f};

    const unsigned short* Ag0 = A + (size_t)(row0 + (tid & 127)) * K + (tid >> 7) * 8;
    const unsigned short* Bg0 = Bt + (size_t)(col0 + (tid & 127)) * K + (tid >> 7) * 8;

    for (int k0 = 0; k0 < K; k0 += 32) {
        __syncthreads();
#if HAS_GLL
        #pragma unroll
        for (int i = 0; i < 2; i++) {
            GLOAD16(Ag0 + k0 + i * 16, &As[(i * 256 + wid * 64) * 8]);
            GLOAD16(Bg0 + k0 + i * 16, &Bs[(i * 256 + wid * 64) * 8]);
        }
#else
        #pragma unroll
        for (int i = 0; i < 2; i++) {
            *(ushort8v*)&As[(size_t)(i * 256 + tid) * 8] = *(const ushort8v*)(Ag0 + k0 + i * 16);
            *(ushort8v*)&Bs[(size_t)(i * 256 + tid) * 8] = *(const ushort8v*)(Bg0 + k0 + i * 16);
        }
#endif
        __syncthreads();
        short8v af[4], bf[4];
        int kb = (lane >> 4) * 1024;
        int lr = (lane & 15) * 8;
        #pragma unroll
        for (int mi = 0; mi < 4; mi++)
            af[mi] = *(const short8v*)&As[kb + (wm + mi * 16) * 8 + lr];
        #pragma unroll
        for (int ni = 0; ni < 4; ni++)
            bf[ni] = *(const short8v*)&Bs[kb + (wn + ni * 16) * 8 + lr];
        #pragma unroll
        for (int mi = 0; mi < 4; mi++)
            #pragma unroll
            for (int ni = 0; ni < 4; ni++)
                acc[mi][ni] = __builtin_amdgcn_mfma_f32_16x16x32_bf16(
                    af[mi], bf[ni], acc[mi][ni], 0, 0, 0);
    }

    // epilogue
    #pragma unroll
    for (int ni = 0; ni < 4; ni++) {
        int col = col0 + wn + ni * 16 + (lane & 15);
        float bv = bias[col];
        #pragma unroll
        for (int mi = 0; mi < 4; mi++) {
            #pragma unroll
            for (int r = 0; r < 4; r++) {
                int grow = row0 + wm + mi * 16 + (lane >> 4) * 4 + r;
                if (grow < M) {
                    float v = acc[mi][ni][r] + bv;
                    if (act) v = silu_f(v);
                    size_t off = (size_t)grow * Nc + col;
                    if (Rf) v += Rf[off];
                    if (Cf) Cf[off] = v;
                    if (Cb) Cb[off] = f2b(v);
                }
            }
        }
    }
}

// ---------------- GINE message + atomic segment-sum (all f32, exact) ---------
__global__ __launch_bounds__(256) void msg_kernel(
    const float* __restrict__ h, const float* __restrict__ mij,
    const int* __restrict__ eidx, const int* __restrict__ emask,
    float* __restrict__ agg)
{
    int e4 = blockIdx.x * 4 + (threadIdx.x >> 6);
    int t = e4 / EK_EDGES;
    int em = emask[e4];
    int src = eidx[em];
    int dst = eidx[E_EDGES + em];
    int f = (threadIdx.x & 63) * 4;
    float4 hv = *(const float4*)(h + (size_t)src * 1024 + t * 256 + f);
    float4 mv = *(const float4*)(mij + (size_t)em * 256 + f);
    float4 s;
    s.x = silu_f(hv.x + mv.x);
    s.y = silu_f(hv.y + mv.y);
    s.z = silu_f(hv.z + mv.z);
    s.w = silu_f(hv.w + mv.w);
    float* ap = agg + ((size_t)t * N_NODES + dst) * 256 + f;
    atomicAdd(ap + 0, s.x);
    atomicAdd(ap + 1, s.y);
    atomicAdd(ap + 2, s.z);
    atomicAdd(ap + 3, s.w);
}

// ---------------- z = agg + xb: f32 in place + bf16 copy ---------------------
__global__ __launch_bounds__(256) void addxb_kernel(const float* __restrict__ h,
    float* __restrict__ zf, unsigned short* __restrict__ zb)
{
    int idx = blockIdx.x * 256 + threadIdx.x;        // per 4 features
    if (idx >= T_TYPES * N_NODES * 64) return;
    int tn = idx >> 6, f4 = (idx & 63) * 4;
    int t = tn / N_NODES, n = tn - t * N_NODES;
    float4 a = *(const float4*)(zf + (size_t)tn * 256 + f4);
    float4 hv = *(const float4*)(h + (size_t)n * 1024 + t * 256 + f4);
    a.x += hv.x; a.y += hv.y; a.z += hv.z; a.w += hv.w;
    *(float4*)(zf + (size_t)tn * 256 + f4) = a;
    ushort4 o;
    o.x = f2b(a.x); o.y = f2b(a.y); o.z = f2b(a.z); o.w = f2b(a.w);
    *(ushort4*)(zb + (size_t)tn * 256 + f4) = o;
}

// ---------------- hid: f32 master + bf16 copy, layout [n*4+t, f] -------------
__global__ __launch_bounds__(256) void hid_kernel(const float* __restrict__ h,
    const float* __restrict__ zf, float* __restrict__ hidf,
    unsigned short* __restrict__ hidb)
{
    int idx = blockIdx.x * 256 + threadIdx.x;        // per 4 features
    if (idx >= N_NODES * T_TYPES * 64) return;
    int nt = idx >> 6, f4 = (idx & 63) * 4;
    int n = nt >> 2, t = nt & 3;
    float4 zv = *(const float4*)(zf + ((size_t)t * N_NODES + n) * 256 + f4);
    float4 hv = *(const float4*)(h + (size_t)nt * 256 + f4);
    float4 o;
    o.x = silu_f(zv.x) + hv.x; o.y = silu_f(zv.y) + hv.y;
    o.z = silu_f(zv.z) + hv.z; o.w = silu_f(zv.w) + hv.w;
    *(float4*)(hidf + (size_t)nt * 256 + f4) = o;
    ushort4 ob;
    ob.x = f2b(o.x); ob.y = f2b(o.y); ob.z = f2b(o.z); ob.w = f2b(o.w);
    *(ushort4*)(hidb + (size_t)nt * 256 + f4) = ob;
}

// ---------------- attention core: per node, 32 heads x 8 dim, 4 tokens -------
// ob may alias qb: each thread reads all its inputs before writing its own slot
__global__ __launch_bounds__(256) void attn_core(const unsigned short* __restrict__ qb,
    const unsigned short* __restrict__ kb, const unsigned short* __restrict__ vb,
    unsigned short* __restrict__ ob)
{
    int tid = threadIdx.x;
    int n = blockIdx.x * 2 + (tid >> 7);
    int local = tid & 127, hh = local >> 2, i = local & 3;
    size_t base = (size_t)n * 1024;
    size_t qoff = base + i * 256 + hh * 8;
    ushort8v qv = *(const ushort8v*)(qb + qoff);
    float q[8];
    #pragma unroll
    for (int d = 0; d < 8; d++) q[d] = b2f(qv[d]);
    const float scale = 0.35355339059327373f;
    float s[4];
    #pragma unroll
    for (int j = 0; j < 4; j++) {
        ushort8v kv = *(const ushort8v*)(kb + base + j * 256 + hh * 8);
        float acc = 0.f;
        #pragma unroll
        for (int d = 0; d < 8; d++) acc += q[d] * b2f(kv[d]);
        s[j] = acc * scale;
    }
    float m = fmaxf(fmaxf(s[0], s[1]), fmaxf(s[2], s[3]));
    float e[4], sum = 0.f;
    #pragma unroll
    for (int j = 0; j < 4; j++) { e[j] = __expf(s[j] - m); sum += e[j]; }
    float inv = 1.0f / sum;
    float o[8] = {};
    #pragma unroll
    for (int j = 0; j < 4; j++) {
        ushort8v vv = *(const ushort8v*)(vb + base + j * 256 + hh * 8);
        float p = e[j] * inv;
        #pragma unroll
        for (int d = 0; d < 8; d++) o[d] += p * b2f(vv[d]);
    }
    ushort8v ov;
    #pragma unroll
    for (int d = 0; d < 8; d++) ov[d] = f2b(o[d]);
    *(ushort8v*)(ob + qoff) = ov;
}

// =============================================================================
extern "C" void kernel_launch(void* const* d_in, const int* in_sizes, int n_in,
                              void* d_out, int out_size, void* d_ws, size_t ws_size,
                              hipStream_t stream)
{
    (void)in_sizes; (void)n_in; (void)out_size; (void)ws_size;
    const float* h     = (const float*)d_in[0];
    const int*   eidx  = (const int*)d_in[1];
    const int*   emask = (const int*)d_in[2];
    const float* nc_w  = (const float*)d_in[3];
    const float* nc_b  = (const float*)d_in[4];
    const float* em_w1 = (const float*)d_in[5];
    const float* em_b1 = (const float*)d_in[6];
    const float* em_w2 = (const float*)d_in[7];
    const float* em_b2 = (const float*)d_in[8];
    const float* em_w3 = (const float*)d_in[9];
    const float* em_b3 = (const float*)d_in[10];
    const float* conv_w = (const float*)d_in[11];
    const float* conv_b = (const float*)d_in[12];
    const float* wq = (const float*)d_in[13]; const float* bq = (const float*)d_in[14];
    const float* wk = (const float*)d_in[15]; const float* bk = (const float*)d_in[16];
    const float* wv = (const float*)d_in[17]; const float* bv = (const float*)d_in[18];
    const float* wo = (const float*)d_in[19]; const float* bo = (const float*)d_in[20];

    float* out = (float*)d_out;                                   // [80000,256] f32
    float* mij = out + (size_t)20480000;                          // [160000,256] f32

    // ---- workspace arena (bytes); max concurrent 188.8 MB ----
    char* w = (char*)d_ws;
    float*          zf  = (float*)w;                              // [0, 81.92M) f32 agg/z
    unsigned short* zb  = (unsigned short*)(w + 81920000);        // 40.96MB bf16 z
    float*          p1f = (float*)(w + 122880000);                // 20.48MB
    float*          p2f = (float*)(w + 143360000);                // 20.48MB
    unsigned short* p1b = (unsigned short*)(w + 163840000);       // 10.24MB
    unsigned short* p2b = (unsigned short*)(w + 174080000);       // 10.24MB
    unsigned short* wts = (unsigned short*)(w + 184320000);       // 4.46MB
    // phase-A aliases (zf/zb/p1f/p2f dead by then)
    unsigned short* qb   = (unsigned short*)w;                    // 40.96MB
    unsigned short* kbuf = (unsigned short*)(w + 40960000);       // 40.96MB
    unsigned short* vbuf = (unsigned short*)(w + 81920000);       // 40.96MB (over zb)
    unsigned short* hidb = (unsigned short*)(w + 122880000);      // 40.96MB (over p1f/p2f)
    unsigned short* ob   = qb;                                    // safe alias

    unsigned short* w1t = wts;                    // [768,512]
    unsigned short* w2t = wts + 393216;           // [512,768]
    unsigned short* w3t = wts + 786432;           // [256,512]
    unsigned short* cwt = wts + 917504;           // 16 x [256,256]
    unsigned short* wqt = wts + 1966080;
    unsigned short* wkt = wts + 2031616;
    unsigned short* wvt = wts + 2097152;
    unsigned short* wot = wts + 2162688;

    // ---- d_out `out`-region overlays (dead before hidf is written) ----
    unsigned short* neb = (unsigned short*)d_out;                       // 10.24MB
    unsigned short* cx  = (unsigned short*)((char*)d_out + 10240000);   // 16.38MB
    unsigned short* ch1 = (unsigned short*)((char*)d_out + 26624000);   // 24.58MB
    unsigned short* ch2 = (unsigned short*)((char*)d_out + 51200000);   // 16.38MB
    float*          hidf = (float*)d_out;                               // full 81.92MB

    hipMemsetAsync(zf, 0, (size_t)81920000, stream);

    // ---- weight transpose/convert ----
    wtrans_kernel<<<dim3(24, 16, 1), 256, 0, stream>>>(em_w1, w1t, 512, 768, 0, 0);
    wtrans_kernel<<<dim3(16, 24, 1), 256, 0, stream>>>(em_w2, w2t, 768, 512, 0, 0);
    wtrans_kernel<<<dim3(8, 16, 1), 256, 0, stream>>>(em_w3, w3t, 512, 256, 0, 0);
    wtrans_kernel<<<dim3(8, 8, 16), 256, 0, stream>>>(conv_w, cwt, 256, 256, 65536, 65536);
    wtrans_kernel<<<dim3(8, 8, 1), 256, 0, stream>>>(wq, wqt, 256, 256, 0, 0);
    wtrans_kernel<<<dim3(8, 8, 1), 256, 0, stream>>>(wk, wkt, 256, 256, 0, 0);
    wtrans_kernel<<<dim3(8, 8, 1), 256, 0, stream>>>(wv, wvt, 256, 256, 0, 0);
    wtrans_kernel<<<dim3(8, 8, 1), 256, 0, stream>>>(wo, wot, 256, 256, 0, 0);

    ne_kernel<<<(N_NODES * 64 + 255) / 256, 256, 0, stream>>>(h, nc_w, nc_b, neb);

    // ---- edge MLP: 512 -> 768 -> 512 -> 256, chunked, mij f32 ----
    for (int c = 0; c < E_EDGES / CH_EDGE; c++) {
        int base = c * CH_EDGE;
        gather_kernel<<<(CH_EDGE * 64) / 256, 256, 0, stream>>>(neb, eidx, base, cx);
        mfma_gemm<<<dim3(6, 125), 256, 0, stream>>>(cx, w1t, em_b1, nullptr,
            nullptr, ch1, CH_EDGE, 512, 768, 1);
        mfma_gemm<<<dim3(4, 125), 256, 0, stream>>>(ch1, w2t, em_b2, nullptr,
            nullptr, ch2, CH_EDGE, 768, 512, 1);
        mfma_gemm<<<dim3(2, 125), 256, 0, stream>>>(ch2, w3t, em_b3, nullptr,
            mij + (size_t)base * 256, nullptr, CH_EDGE, 512, 256, 0);
    }

    // ---- GINE scatter (f32 exact) + z = agg + xb ----
    msg_kernel<<<(T_TYPES * EK_EDGES) / 4, 256, 0, stream>>>(h, mij, eidx, emask, zf);
    addxb_kernel<<<(T_TYPES * N_NODES * 64) / 256, 256, 0, stream>>>(h, zf, zb);

    // ---- conv MLP: per type, 4 residual layers; f32 residuals, bf16 A ----
    for (int t = 0; t < T_TYPES; t++) {
        unsigned short* zbt = zb + (size_t)t * N_NODES * 256;
        float* zft = zf + (size_t)t * N_NODES * 256;
        const unsigned short* cw = cwt + (size_t)t * 4 * 65536;
        const float* cb = conv_b + (size_t)t * 4 * 256;
        dim3 g(2, 157);
        mfma_gemm<<<g, 256, 0, stream>>>(zbt, cw,          cb,       zft, p1f, p1b, N_NODES, 256, 256, 1);
        mfma_gemm<<<g, 256, 0, stream>>>(p1b, cw + 65536,  cb + 256, p1f, p2f, p2b, N_NODES, 256, 256, 1);
        mfma_gemm<<<g, 256, 0, stream>>>(p2b, cw + 131072, cb + 512, p2f, p1f, p1b, N_NODES, 256, 256, 1);
        mfma_gemm<<<g, 256, 0, stream>>>(p1b, cw + 196608, cb + 768, p1f, zft, nullptr, N_NODES, 256, 256, 0);
    }

    // ---- hid: f32 master in d_out region + bf16 copy ----
    hid_kernel<<<(N_NODES * T_TYPES * 64) / 256, 256, 0, stream>>>(h, zf, hidf, hidb);

    // ---- attention projections (M=80000, exact tiles), bf16 out ----
    mfma_gemm<<<dim3(2, 625), 256, 0, stream>>>(hidb, wqt, bq, nullptr, nullptr, qb,   80000, 256, 256, 0);
    mfma_gemm<<<dim3(2, 625), 256, 0, stream>>>(hidb, wkt, bk, nullptr, nullptr, kbuf, 80000, 256, 256, 0);
    mfma_gemm<<<dim3(2, 625), 256, 0, stream>>>(hidb, wvt, bv, nullptr, nullptr, vbuf, 80000, 256, 256, 0);

    attn_core<<<N_NODES / 2, 256, 0, stream>>>(qb, kbuf, vbuf, ob);

    // ---- output projection + f32 residual, in-place over hidf ----
    mfma_gemm<<<dim3(2, 625), 256, 0, stream>>>(ob, wot, bo, hidf, out, nullptr, 80000, 256, 256, 0);
}

// Round 4
// 2422.204 us; speedup vs baseline: 2.6586x; 1.2674x over previous
//
#include <hip/hip_runtime.h>
#include <math.h>

#define N_NODES 20000
#define T_TYPES 4
#define H_DIM   256
#define E_EDGES 160000
#define EK_EDGES 40000
#define CH_EDGE 40000
#define BCAP    32

typedef __attribute__((ext_vector_type(8))) short short8v;
typedef __attribute__((ext_vector_type(8))) unsigned short ushort8v;
typedef __attribute__((ext_vector_type(4))) float f32x4;

__device__ __forceinline__ float silu_f(float x) {
    return x / (1.0f + __expf(-x));
}
__device__ __forceinline__ float b2f(unsigned short u) {
    union { unsigned int i; float f; } v; v.i = ((unsigned int)u) << 16; return v.f;
}
__device__ __forceinline__ unsigned short f2b(float f) {
    union { unsigned int i; float f; } v; v.f = f;
    unsigned int r = v.i + 0x7FFF + ((v.i >> 16) & 1);
    return (unsigned short)(r >> 16);
}

#if __has_builtin(__builtin_amdgcn_global_load_lds)
#define HAS_GLL 1
#define GLOAD16(g, l) __builtin_amdgcn_global_load_lds( \
    (const __attribute__((address_space(1))) void*)(g), \
    (__attribute__((address_space(3))) void*)(l), 16, 0, 0)
#else
#define HAS_GLL 0
#endif

// ---------------- weight transpose+convert: W [K,N] f32 -> Wt [N,K] bf16 -----
__global__ __launch_bounds__(256) void wtrans_kernel(const float* __restrict__ W,
    unsigned short* __restrict__ Wt, int K, int N, long sW, long sWt)
{
    __shared__ float tile[32][33];
    const float* Wz = W + (size_t)blockIdx.z * sW;
    unsigned short* Wtz = Wt + (size_t)blockIdx.z * sWt;
    int tx = threadIdx.x & 31, ty = threadIdx.x >> 5;
    #pragma unroll
    for (int r = ty; r < 32; r += 8) {
        int gr = blockIdx.y * 32 + r, gc = blockIdx.x * 32 + tx;
        tile[r][tx] = Wz[(size_t)gr * N + gc];
    }
    __syncthreads();
    #pragma unroll
    for (int r = ty; r < 32; r += 8) {
        int gn = blockIdx.x * 32 + r, gk = blockIdx.y * 32 + tx;
        Wtz[(size_t)gn * K + gk] = f2b(tile[tx][r]);
    }
}

// ---------------- concat q/k/v biases into one f32[768] ----------------------
__global__ void concat_bias(const float* __restrict__ bq, const float* __restrict__ bk,
    const float* __restrict__ bv, float* __restrict__ b768)
{
    int i = threadIdx.x;
    b768[i] = (i < 256) ? bq[i] : (i < 512 ? bk[i - 256] : bv[i - 512]);
}

// ---------------- node_emb -> bf16 ------------------------------------------
__global__ __launch_bounds__(256) void ne_kernel(const float* __restrict__ h,
    const float* __restrict__ nc_w, const float* __restrict__ nc_b,
    unsigned short* __restrict__ neb)
{
    int idx = blockIdx.x * 256 + threadIdx.x;         // per 4 features
    if (idx >= N_NODES * 64) return;
    int n = idx >> 6, f4 = (idx & 63) * 4;
    const float* hp = h + (size_t)n * 1024 + f4;
    float4 a = *(const float4*)hp;
    float4 b = *(const float4*)(hp + 256);
    float4 c = *(const float4*)(hp + 512);
    float4 d = *(const float4*)(hp + 768);
    float w0 = nc_w[0], w1 = nc_w[1], w2 = nc_w[2], w3 = nc_w[3], bb = nc_b[0];
    ushort4 o;
    o.x = f2b(a.x * w0 + b.x * w1 + c.x * w2 + d.x * w3 + bb);
    o.y = f2b(a.y * w0 + b.y * w1 + c.y * w2 + d.y * w3 + bb);
    o.z = f2b(a.z * w0 + b.z * w1 + c.z * w2 + d.z * w3 + bb);
    o.w = f2b(a.w * w0 + b.w * w1 + c.w * w2 + d.w * w3 + bb);
    *(ushort4*)(neb + (size_t)n * 256 + f4) = o;
}

// ---------------- gather [ne[src]||ne[tgt]] bf16 for an edge chunk -----------
__global__ __launch_bounds__(256) void gather_kernel(const unsigned short* __restrict__ neb,
    const int* __restrict__ eidx, int base, unsigned short* __restrict__ cx)
{
    int idx = blockIdx.x * 256 + threadIdx.x;         // per 8 bf16
    int row = idx >> 6, f8 = idx & 63;
    int e = base + row;
    int node = (f8 < 32) ? eidx[e] : eidx[E_EDGES + e];
    ushort8v v = *(const ushort8v*)(neb + (size_t)node * 256 + (f8 & 31) * 8);
    *(ushort8v*)(cx + (size_t)row * 512 + f8 * 8) = v;
}

// ---------------- bf16 MFMA GEMM: C = act(A@Bt^T + bias) (+Rf f32) -----------
// A [M,K] bf16 with leading-dim lda (rows to next 128-mult must be readable),
// Bt [Nc,K] bf16 rowmajor, bias f32 [Nc], Rf optional f32 residual (ldr).
// Stores: Cf f32 and/or Cb bf16 at grow*ldc + cbase + col.
__global__ __launch_bounds__(256) void mfma_gemm(
    const unsigned short* __restrict__ A, long lda,
    const unsigned short* __restrict__ Bt,
    const float* __restrict__ bias,
    const float* __restrict__ Rf, long ldr,
    float* __restrict__ Cf, unsigned short* __restrict__ Cb, long ldc, long cbase,
    int M, int K, int Nc, int act)
{
    __shared__ unsigned short As[4096];   // chunk c = k8*128+row, 8 elts (16B)
    __shared__ unsigned short Bs[4096];
    int tid = threadIdx.x;
    int wid = tid >> 6, lane = tid & 63;
    int row0 = blockIdx.y * 128, col0 = blockIdx.x * 128;
    int wm = (wid >> 1) * 64, wn = (wid & 1) * 64;

    f32x4 acc[4][4];
    #pragma unroll
    for (int i = 0; i < 4; i++)
        #pragma unroll
        for (int j = 0; j < 4; j++)
            acc[i][j] = (f32x4){0.f, 0.f, 0.f, 0.f};

    const unsigned short* Ag0 = A + (size_t)(row0 + (tid & 127)) * lda + (tid >> 7) * 8;
    const unsigned short* Bg0 = Bt + (size_t)(col0 + (tid & 127)) * K + (tid >> 7) * 8;

    for (int k0 = 0; k0 < K; k0 += 32) {
        __syncthreads();
#if HAS_GLL
        #pragma unroll
        for (int i = 0; i < 2; i++) {
            GLOAD16(Ag0 + k0 + i * 16, &As[(i * 256 + wid * 64) * 8]);
            GLOAD16(Bg0 + k0 + i * 16, &Bs[(i * 256 + wid * 64) * 8]);
        }
#else
        #pragma unroll
        for (int i = 0; i < 2; i++) {
            *(ushort8v*)&As[(size_t)(i * 256 + tid) * 8] = *(const ushort8v*)(Ag0 + k0 + i * 16);
            *(ushort8v*)&Bs[(size_t)(i * 256 + tid) * 8] = *(const ushort8v*)(Bg0 + k0 + i * 16);
        }
#endif
        __syncthreads();
        short8v af[4], bf[4];
        int kb = (lane >> 4) * 1024;
        int lr = (lane & 15) * 8;
        #pragma unroll
        for (int mi = 0; mi < 4; mi++)
            af[mi] = *(const short8v*)&As[kb + (wm + mi * 16) * 8 + lr];
        #pragma unroll
        for (int ni = 0; ni < 4; ni++)
            bf[ni] = *(const short8v*)&Bs[kb + (wn + ni * 16) * 8 + lr];
        #pragma unroll
        for (int mi = 0; mi < 4; mi++)
            #pragma unroll
            for (int ni = 0; ni < 4; ni++)
                acc[mi][ni] = __builtin_amdgcn_mfma_f32_16x16x32_bf16(
                    af[mi], bf[ni], acc[mi][ni], 0, 0, 0);
    }

    // epilogue
    #pragma unroll
    for (int ni = 0; ni < 4; ni++) {
        int col = col0 + wn + ni * 16 + (lane & 15);
        float bv = bias[col];
        #pragma unroll
        for (int mi = 0; mi < 4; mi++) {
            #pragma unroll
            for (int r = 0; r < 4; r++) {
                int grow = row0 + wm + mi * 16 + (lane >> 4) * 4 + r;
                if (grow < M) {
                    float v = acc[mi][ni][r] + bv;
                    if (act) v = silu_f(v);
                    size_t off_c = (size_t)grow * ldc + cbase + col;
                    if (Rf) v += Rf[(size_t)grow * ldr + col];
                    if (Cf) Cf[off_c] = v;
                    if (Cb) Cb[off_c] = f2b(v);
                }
            }
        }
    }
}

// ---------------- GINE bucket build: cnt/slots keyed by (t, dst) -------------
__global__ __launch_bounds__(256) void gine_hist(const int* __restrict__ eidx,
    const int* __restrict__ emask, int* __restrict__ cnt, int* __restrict__ slots)
{
    int idx = blockIdx.x * 256 + threadIdx.x;       // [0, T*EK)
    int t = idx / EK_EDGES;
    int em = emask[idx];
    int dst = eidx[E_EDGES + em];
    int tn = t * N_NODES + dst;
    int pos = atomicAdd(&cnt[tn], 1);
    if (pos < BCAP) slots[tn * BCAP + pos] = em;
}

// ---------------- GINE gather: z[t,n,:] = xb + sum silu(h[src]+mij[em]) ------
// one wave per (t,n) row; writes zf f32 + zb bf16. No atomics, no memset.
__global__ __launch_bounds__(256) void gine_gather(
    const float* __restrict__ h, const float* __restrict__ mij,
    const int* __restrict__ eidx, const int* __restrict__ cnt,
    const int* __restrict__ slots, float* __restrict__ zf,
    unsigned short* __restrict__ zb)
{
    int tn = blockIdx.x * 4 + (threadIdx.x >> 6);
    int lane = threadIdx.x & 63;
    int t = tn / N_NODES, n = tn - t * N_NODES;
    int f = lane * 4;
    int deg = cnt[tn]; if (deg > BCAP) deg = BCAP;
    float4 acc = *(const float4*)(h + (size_t)n * 1024 + t * 256 + f);   // xb
    for (int j = 0; j < deg; j++) {
        int em = slots[tn * BCAP + j];
        int src = eidx[em];
        float4 hv = *(const float4*)(h + (size_t)src * 1024 + t * 256 + f);
        float4 mv = *(const float4*)(mij + (size_t)em * 256 + f);
        acc.x += silu_f(hv.x + mv.x);
        acc.y += silu_f(hv.y + mv.y);
        acc.z += silu_f(hv.z + mv.z);
        acc.w += silu_f(hv.w + mv.w);
    }
    *(float4*)(zf + (size_t)tn * 256 + f) = acc;
    ushort4 o;
    o.x = f2b(acc.x); o.y = f2b(acc.y); o.z = f2b(acc.z); o.w = f2b(acc.w);
    *(ushort4*)(zb + (size_t)tn * 256 + f) = o;
}

// ---------------- hid: f32 master + bf16 copy, layout [n*4+t, f] -------------
__global__ __launch_bounds__(256) void hid_kernel(const float* __restrict__ h,
    const float* __restrict__ zf, float* __restrict__ hidf,
    unsigned short* __restrict__ hidb)
{
    int idx = blockIdx.x * 256 + threadIdx.x;        // per 4 features
    if (idx >= N_NODES * T_TYPES * 64) return;
    int nt = idx >> 6, f4 = (idx & 63) * 4;
    int n = nt >> 2, t = nt & 3;
    float4 zv = *(const float4*)(zf + ((size_t)t * N_NODES + n) * 256 + f4);
    float4 hv = *(const float4*)(h + (size_t)nt * 256 + f4);
    float4 o;
    o.x = silu_f(zv.x) + hv.x; o.y = silu_f(zv.y) + hv.y;
    o.z = silu_f(zv.z) + hv.z; o.w = silu_f(zv.w) + hv.w;
    *(float4*)(hidf + (size_t)nt * 256 + f4) = o;
    ushort4 ob;
    ob.x = f2b(o.x); ob.y = f2b(o.y); ob.z = f2b(o.z); ob.w = f2b(o.w);
    *(ushort4*)(hidb + (size_t)nt * 256 + f4) = ob;
}

// ---------------- attention core on interleaved qkv [80000, 768] bf16 --------
// o written in-place over the q slot (owner-thread read-before-write: safe)
__global__ __launch_bounds__(256) void attn_core(unsigned short* __restrict__ qkv)
{
    int tid = threadIdx.x;
    int n = blockIdx.x * 2 + (tid >> 7);
    int local = tid & 127, hh = local >> 2, i = local & 3;
    size_t rb = (size_t)n * 4 * 768;
    size_t qoff = rb + (size_t)i * 768 + hh * 8;
    ushort8v qv = *(const ushort8v*)(qkv + qoff);
    float q[8];
    #pragma unroll
    for (int d = 0; d < 8; d++) q[d] = b2f(qv[d]);
    const float scale = 0.35355339059327373f;   // 1/sqrt(8)
    float s[4];
    #pragma unroll
    for (int j = 0; j < 4; j++) {
        ushort8v kv = *(const ushort8v*)(qkv + rb + (size_t)j * 768 + 256 + hh * 8);
        float acc = 0.f;
        #pragma unroll
        for (int d = 0; d < 8; d++) acc += q[d] * b2f(kv[d]);
        s[j] = acc * scale;
    }
    float m = fmaxf(fmaxf(s[0], s[1]), fmaxf(s[2], s[3]));
    float e[4], sum = 0.f;
    #pragma unroll
    for (int j = 0; j < 4; j++) { e[j] = __expf(s[j] - m); sum += e[j]; }
    float inv = 1.0f / sum;
    float o[8] = {};
    #pragma unroll
    for (int j = 0; j < 4; j++) {
        ushort8v vv = *(const ushort8v*)(qkv + rb + (size_t)j * 768 + 512 + hh * 8);
        float p = e[j] * inv;
        #pragma unroll
        for (int d = 0; d < 8; d++) o[d] += p * b2f(vv[d]);
    }
    ushort8v ov;
    #pragma unroll
    for (int d = 0; d < 8; d++) ov[d] = f2b(o[d]);
    *(ushort8v*)(qkv + qoff) = ov;
}

// =============================================================================
extern "C" void kernel_launch(void* const* d_in, const int* in_sizes, int n_in,
                              void* d_out, int out_size, void* d_ws, size_t ws_size,
                              hipStream_t stream)
{
    (void)in_sizes; (void)n_in; (void)out_size; (void)ws_size;
    const float* h     = (const float*)d_in[0];
    const int*   eidx  = (const int*)d_in[1];
    const int*   emask = (const int*)d_in[2];
    const float* nc_w  = (const float*)d_in[3];
    const float* nc_b  = (const float*)d_in[4];
    const float* em_w1 = (const float*)d_in[5];
    const float* em_b1 = (const float*)d_in[6];
    const float* em_w2 = (const float*)d_in[7];
    const float* em_b2 = (const float*)d_in[8];
    const float* em_w3 = (const float*)d_in[9];
    const float* em_b3 = (const float*)d_in[10];
    const float* conv_w = (const float*)d_in[11];
    const float* conv_b = (const float*)d_in[12];
    const float* wq = (const float*)d_in[13]; const float* bq = (const float*)d_in[14];
    const float* wk = (const float*)d_in[15]; const float* bk = (const float*)d_in[16];
    const float* wv = (const float*)d_in[17]; const float* bv = (const float*)d_in[18];
    const float* wo = (const float*)d_in[19]; const float* bo = (const float*)d_in[20];

    float* out = (float*)d_out;                                   // [80000,256] f32
    float* mij = out + (size_t)20480000;                          // [160000,256] f32

    // ---- workspace arena (bytes); peak ~188.8 MB (R1 proved ws >= 232 MB) ---
    char* w = (char*)d_ws;
    // phase E (edge MLP) staging
    unsigned short* cx  = (unsigned short*)w;                     // 40.96 MB
    unsigned short* ch1 = (unsigned short*)(w + 40960000);        // 61.44 MB
    unsigned short* ch2 = (unsigned short*)(w + 102400000);       // 40.96 MB
    // phase G (GINE)
    float*          zf  = (float*)w;                              // 81.92 MB
    unsigned short* zb  = (unsigned short*)(w + 81920000);        // 40.96 MB
    int*            cnt   = (int*)(w + 143360000);                // 0.32 MB
    int*            slots = (int*)(w + 143680000);                // 10.24 MB
    // conv phase
    float*          p1f = (float*)(w + 122880000);                // 20.48 MB
    float*          p2f = (float*)(w + 143360000);                // 20.48 MB (over cnt/slots)
    unsigned short* p1b = (unsigned short*)(w + 163840000);       // 10.24 MB
    unsigned short* p2b = (unsigned short*)(w + 174080000);       // 10.24 MB
    // persistent weights
    unsigned short* wts = (unsigned short*)(w + 184320000);       // 4.46 MB
    float*          bias768 = (float*)(w + 188780032);            // 3 KB
    // phase A (attention)
    unsigned short* qkv  = (unsigned short*)w;                    // 122.88 MB (over zf/zb)
    unsigned short* hidb = (unsigned short*)(w + 122880000);      // 40.96 MB (over p1f/p2f)

    unsigned short* w1t   = wts;                    // [768,512]
    unsigned short* w2t   = wts + 393216;           // [512,768]
    unsigned short* w3t   = wts + 786432;           // [256,512]
    unsigned short* cwt   = wts + 917504;           // 16 x [256,256]
    unsigned short* wqkvt = wts + 1966080;          // [768,256]
    unsigned short* wot   = wts + 2162688;          // [256,256]

    // ---- d_out overlays ----
    unsigned short* neb = (unsigned short*)d_out;                 // 10.24 MB (out region)
    float*          hidf = (float*)d_out;                         // f32 hid master

    // ---- weight transpose/convert + bias concat ----
    wtrans_kernel<<<dim3(24, 16, 1), 256, 0, stream>>>(em_w1, w1t, 512, 768, 0, 0);
    wtrans_kernel<<<dim3(16, 24, 1), 256, 0, stream>>>(em_w2, w2t, 768, 512, 0, 0);
    wtrans_kernel<<<dim3(8, 16, 1), 256, 0, stream>>>(em_w3, w3t, 512, 256, 0, 0);
    wtrans_kernel<<<dim3(8, 8, 16), 256, 0, stream>>>(conv_w, cwt, 256, 256, 65536, 65536);
    wtrans_kernel<<<dim3(8, 8, 1), 256, 0, stream>>>(wq, wqkvt,          256, 256, 0, 0);
    wtrans_kernel<<<dim3(8, 8, 1), 256, 0, stream>>>(wk, wqkvt + 65536,  256, 256, 0, 0);
    wtrans_kernel<<<dim3(8, 8, 1), 256, 0, stream>>>(wv, wqkvt + 131072, 256, 256, 0, 0);
    wtrans_kernel<<<dim3(8, 8, 1), 256, 0, stream>>>(wo, wot, 256, 256, 0, 0);
    concat_bias<<<1, 768, 0, stream>>>(bq, bk, bv, bias768);

    ne_kernel<<<(N_NODES * 64 + 255) / 256, 256, 0, stream>>>(h, nc_w, nc_b, neb);

    // GINE buckets (independent of mij; region disjoint from edge staging)
    hipMemsetAsync(cnt, 0, T_TYPES * N_NODES * 4, stream);
    gine_hist<<<(T_TYPES * EK_EDGES) / 256, 256, 0, stream>>>(eidx, emask, cnt, slots);

    // ---- edge MLP: 512 -> 768 -> 512 -> 256, 4 chunks of 40000 ----
    for (int c = 0; c < E_EDGES / CH_EDGE; c++) {
        int base = c * CH_EDGE;
        gather_kernel<<<(CH_EDGE * 64) / 256, 256, 0, stream>>>(neb, eidx, base, cx);
        mfma_gemm<<<dim3(6, 313), 256, 0, stream>>>(cx, 512, w1t, em_b1,
            nullptr, 0, nullptr, ch1, 768, 0, CH_EDGE, 512, 768, 1);
        mfma_gemm<<<dim3(4, 313), 256, 0, stream>>>(ch1, 768, w2t, em_b2,
            nullptr, 0, nullptr, ch2, 512, 0, CH_EDGE, 768, 512, 1);
        mfma_gemm<<<dim3(2, 313), 256, 0, stream>>>(ch2, 512, w3t, em_b3,
            nullptr, 0, mij + (size_t)base * 256, nullptr, 256, 0, CH_EDGE, 512, 256, 0);
    }

    // ---- GINE gather: z = xb + sum silu(h[src]+mij), f32+bf16 ----
    gine_gather<<<T_TYPES * N_NODES / 4, 256, 0, stream>>>(h, mij, eidx, cnt, slots, zf, zb);

    // ---- conv MLP: per type, 4 residual layers; f32 residuals, bf16 A ----
    for (int t = 0; t < T_TYPES; t++) {
        unsigned short* zbt = zb + (size_t)t * N_NODES * 256;
        float* zft = zf + (size_t)t * N_NODES * 256;
        const unsigned short* cw = cwt + (size_t)t * 4 * 65536;
        const float* cb = conv_b + (size_t)t * 4 * 256;
        dim3 g(2, 157);
        mfma_gemm<<<g, 256, 0, stream>>>(zbt, 256, cw,          cb,       zft, 256, p1f, p1b, 256, 0, N_NODES, 256, 256, 1);
        mfma_gemm<<<g, 256, 0, stream>>>(p1b, 256, cw + 65536,  cb + 256, p1f, 256, p2f, p2b, 256, 0, N_NODES, 256, 256, 1);
        mfma_gemm<<<g, 256, 0, stream>>>(p2b, 256, cw + 131072, cb + 512, p2f, 256, p1f, p1b, 256, 0, N_NODES, 256, 256, 1);
        mfma_gemm<<<g, 256, 0, stream>>>(p1b, 256, cw + 196608, cb + 768, p1f, 256, zft, nullptr, 256, 0, N_NODES, 256, 256, 0);
    }

    // ---- hid: f32 master in d_out + bf16 copy ----
    hid_kernel<<<(N_NODES * T_TYPES * 64) / 256, 256, 0, stream>>>(h, zf, hidf, hidb);

    // ---- fused QKV projection -> interleaved qkv [80000,768] bf16 ----
    mfma_gemm<<<dim3(6, 625), 256, 0, stream>>>(hidb, 256, wqkvt, bias768,
        nullptr, 0, nullptr, qkv, 768, 0, 80000, 256, 768, 0);

    attn_core<<<N_NODES / 2, 256, 0, stream>>>(qkv);

    // ---- output projection + f32 residual (A = o slots of qkv, lda=768) ----
    mfma_gemm<<<dim3(2, 625), 256, 0, stream>>>(qkv, 768, wot, bo,
        hidf, 256, out, nullptr, 256, 0, 80000, 256, 256, 0);
}